// Round 8
// baseline (1149.332 us; speedup 1.0000x reference)
//
#include <hip/hip_runtime.h>
#include <hip/hip_bf16.h>

#define NN 100000
#define EE 640000
#define NB_SCAN 98   // ceil(NN/1024)
#define G_E7 512     // k_edge7: 512 blocks x 8 waves = 4096 waves, grid-stride 40000 tiles

typedef short bf16x8 __attribute__((ext_vector_type(8)));
typedef float f32x4 __attribute__((ext_vector_type(4)));

__device__ __forceinline__ ushort f2bf(float f){
  uint u = __float_as_uint(f);
  u += 0x7fffu + ((u >> 16) & 1u);   // round-to-nearest-even
  return (ushort)(u >> 16);
}
__device__ __forceinline__ float bf2f(ushort s){ return __uint_as_float(((uint)s) << 16); }
__device__ __forceinline__ uint pack2(float a, float b){ return ((uint)f2bf(b) << 16) | (uint)f2bf(a); }
__device__ __forceinline__ uint swz(uint row, uint colB, uint strideB){
  return row * strideB + (colB ^ ((row & 7u) << 4));
}

// ---------------- K0: weight prep (fp32 -> bf16, transposed [col][k]) + zero deg -----
__global__ void k_prep(const float* __restrict__ Wq, const float* __restrict__ Wk,
                       const float* __restrict__ Wv, const float* __restrict__ Wsk,
                       const float* __restrict__ We,
                       ushort* __restrict__ W4t, ushort* __restrict__ Wet,
                       int* __restrict__ deg){
  int tid = blockIdx.x * 256 + threadIdx.x;
  if (tid < 512 * 128){              // W4t[col 0..511][k 0..127], cols: q|k|v|skip
    int col = tid >> 7, k = tid & 127;
    const float* W = (col < 128) ? Wq : ((col < 256) ? Wk : ((col < 384) ? Wv : Wsk));
    W4t[tid] = f2bf(W[k * 128 + (col & 127)]);
  }
  if (tid < 128 * 256){              // Wet[col 0..127][k 0..255]
    int col = tid >> 8, k = tid & 255;
    Wet[tid] = f2bf(We[k * 128 + col]);
  }
  if (tid < NN) deg[tid] = 0;
}

// ---------------- K1: node GEMM x@[Wq|Wk|Wv|Wskip], 64-row tiles, bf16 MFMA ----------
__global__ __launch_bounds__(256) void k_node(
    const float* __restrict__ x, const ushort* __restrict__ W4t,
    const float* __restrict__ bq, const float* __restrict__ bk,
    const float* __restrict__ bv, const float* __restrict__ bsk,
    ushort* __restrict__ q_n, ushort* __restrict__ kv,
    float* __restrict__ out){
  __shared__ ushort As[64 * 128];
  __shared__ ushort Bs[128 * 128];
  char* Ab = (char*)As; char* Bb = (char*)Bs;
  int tid = threadIdx.x;
  int n0 = blockIdx.x * 64;
  {
    int row = tid >> 2, part = tid & 3;
    int gr = n0 + row;
    for (int j = 0; j < 4; j++){
      float4 a = make_float4(0.f,0.f,0.f,0.f), b = a;
      if (gr < NN){
        const float4* p = (const float4*)(x + (size_t)gr * 128 + part * 32 + j * 8);
        a = p[0]; b = p[1];
      }
      uint4 w; w.x = pack2(a.x,a.y); w.y = pack2(a.z,a.w); w.z = pack2(b.x,b.y); w.w = pack2(b.z,b.w);
      *(uint4*)(Ab + swz(row, (uint)(part * 64 + j * 16), 256)) = w;
    }
  }
  int wid = tid >> 6, l = tid & 63, lr = l & 15, lg = l >> 4;
  for (int chunk = 0; chunk < 4; ++chunk){
    if (chunk) __syncthreads();
    {
      int row = tid >> 1, half = tid & 1;
      const ushort* src = W4t + (size_t)(chunk * 128 + row) * 128 + half * 64;
      for (int j = 0; j < 8; j++){
        uint4 w = *(const uint4*)(src + j * 8);
        *(uint4*)(Bb + swz(row, (uint)(half * 128 + j * 16), 256)) = w;
      }
    }
    __syncthreads();
    f32x4 acc[8];
    for (int i = 0; i < 8; i++) acc[i] = (f32x4){0.f,0.f,0.f,0.f};
    for (int ks = 0; ks < 4; ++ks){
      bf16x8 a = *(bf16x8*)(Ab + swz(wid * 16 + lr, (uint)(ks * 64 + lg * 16), 256));
      for (int cf = 0; cf < 8; ++cf){
        bf16x8 b = *(bf16x8*)(Bb + swz(cf * 16 + lr, (uint)(ks * 64 + lg * 16), 256));
        acc[cf] = __builtin_amdgcn_mfma_f32_16x16x32_bf16(a, b, acc[cf], 0, 0, 0);
      }
    }
    for (int cf = 0; cf < 8; ++cf){
      for (int i = 0; i < 4; i++){
        int row = wid * 16 + lg * 4 + i;
        int gr = n0 + row;
        if (gr >= NN) continue;
        int col = cf * 16 + lr;
        float v = acc[cf][i];
        if (chunk == 0)      q_n[(size_t)gr * 128 + col] = f2bf(v + bq[col]);
        else if (chunk == 1) kv[(size_t)gr * 256 + ((col >> 1) << 2) + (col & 1)]     = f2bf(v + bk[col]);
        else if (chunk == 2) kv[(size_t)gr * 256 + ((col >> 1) << 2) + 2 + (col & 1)] = f2bf(v + bv[col]);
        else                 out[(size_t)gr * 128 + col] = v + bsk[col];
      }
    }
  }
}

// ---------------- k_rel: rel[e] = t[e] - lu[src[e]] ----------------------------------
__global__ void k_rel(const float* __restrict__ tt, const float* __restrict__ lu,
                      const int* __restrict__ ei, float* __restrict__ rel){
  int e = blockIdx.x * 256 + threadIdx.x;
  if (e < EE) rel[e] = tt[e] - lu[ei[e]];
}

// ---------------- K2 v7: edge GEMM, We^T in LDS, independent waves, dup=1 -------------
// We^T (128 ch x 256 k, bf16 = 64KB) staged into LDS once, XOR-swizzled; zero barriers
// after that. Each wave owns a full 16-edge x 128-ch tile: msg read once, cos computed
// once. Next tile's msg loads issued before the 64-MFMA block (fly under compute).
__global__ __launch_bounds__(512, 4) void k_edge7(
    const float* __restrict__ rel, const float* __restrict__ msg,
    const float* __restrict__ tw, const float* __restrict__ tb,
    const ushort* __restrict__ Wet, ushort* __restrict__ ep){
  __shared__ ushort Wl[128 * 256];   // 64 KB, row=channel (512B), col-XOR ^((row&7)<<4)
  char* WL = (char*)Wl;
  int tid = threadIdx.x;
  { // stage Wet -> LDS (once)
    int row = tid >> 2, part = tid & 3;
    const ushort* src = Wet + (size_t)row * 256 + part * 64;
    char* dstrow = WL + row * 512;
    #pragma unroll
    for (int j = 0; j < 8; ++j){
      uint4 v = *(const uint4*)(src + j * 8);
      *(uint4*)(dstrow + (((uint)(part * 128 + j * 16)) ^ (((uint)row & 7u) << 4))) = v;
    }
  }
  __syncthreads();
  int wid = tid >> 6, l = tid & 63, lr = l & 15, lg = l >> 4;
  uint sx = ((uint)lr & 7u) << 4;    // per-lane XOR term ((cf*16+lr)&7 == lr&7)
  const int NT = EE / 16;
  int tile = (int)blockIdx.x * 8 + wid;   // stride 4096
  float4 m[8]; float relN = 0.f;
  { // prologue: issue tile-0 loads
    const float* MB = msg + (size_t)(tile * 16 + lr) * 128 + lg * 8;
    #pragma unroll
    for (int ks = 0; ks < 4; ++ks){
      m[2*ks]   = *(const float4*)(MB + ks * 32);
      m[2*ks+1] = *(const float4*)(MB + ks * 32 + 4);
    }
    relN = rel[tile * 16 + lr];
  }
  while (true){
    float relv = relN;
    bf16x8 B[8];
    #pragma unroll
    for (int ks = 0; ks < 4; ++ks){     // k = ks*32 + lg*8 : cos features (dup=1)
      int k0 = ks * 32 + lg * 8;
      float4 wa = *(const float4*)(tw + k0), wb = *(const float4*)(tw + k0 + 4);
      float4 ba = *(const float4*)(tb + k0), bb = *(const float4*)(tb + k0 + 4);
      float c0 = __cosf(fmaf(relv, wa.x, ba.x));
      float c1 = __cosf(fmaf(relv, wa.y, ba.y));
      float c2 = __cosf(fmaf(relv, wa.z, ba.z));
      float c3 = __cosf(fmaf(relv, wa.w, ba.w));
      float c4 = __cosf(fmaf(relv, wb.x, bb.x));
      float c5 = __cosf(fmaf(relv, wb.y, bb.y));
      float c6 = __cosf(fmaf(relv, wb.z, bb.z));
      float c7 = __cosf(fmaf(relv, wb.w, bb.w));
      uint4 w; w.x = pack2(c0,c1); w.y = pack2(c2,c3); w.z = pack2(c4,c5); w.w = pack2(c6,c7);
      B[ks] = *(bf16x8*)&w;
    }
    #pragma unroll
    for (int ks = 0; ks < 4; ++ks){     // k = 128+ : msg features (vmcnt waits here)
      float4 a = m[2*ks], b = m[2*ks+1];
      uint4 w; w.x = pack2(a.x,a.y); w.y = pack2(a.z,a.w); w.z = pack2(b.x,b.y); w.w = pack2(b.z,b.w);
      B[4+ks] = *(bf16x8*)&w;
    }
    int cur = tile;
    tile += G_E7 * 8;
    if (tile < NT){ // issue next tile's loads; they land under the MFMA block below
      const float* MB = msg + (size_t)(tile * 16 + lr) * 128 + lg * 8;
      #pragma unroll
      for (int ks = 0; ks < 4; ++ks){
        m[2*ks]   = *(const float4*)(MB + ks * 32);
        m[2*ks+1] = *(const float4*)(MB + ks * 32 + 4);
      }
      relN = rel[tile * 16 + lr];
    }
    f32x4 acc[8];
    #pragma unroll
    for (int cf = 0; cf < 8; ++cf) acc[cf] = (f32x4){0.f,0.f,0.f,0.f};
    #pragma unroll
    for (int ks = 0; ks < 8; ++ks){
      uint kb = ((uint)(ks * 64 + lg * 16)) ^ sx;
      #pragma unroll
      for (int cf = 0; cf < 8; ++cf){
        bf16x8 a = *(bf16x8*)(WL + (cf * 16 + lr) * 512 + kb);
        acc[cf] = __builtin_amdgcn_mfma_f32_16x16x32_bf16(a, B[ks], acc[cf], 0, 0, 0);
      }
    }
    #pragma unroll
    for (int cf = 0; cf < 8; ++cf){     // D: col(lr)=edge, row(lg*4+i)=channel
      uint2 w = make_uint2(pack2(acc[cf][0], acc[cf][1]), pack2(acc[cf][2], acc[cf][3]));
      *(uint2*)(ep + (size_t)(cur * 16 + lr) * 128 + cf * 16 + lg * 4) = w;
    }
    if (tile >= NT) break;
  }
}

// ---------------- Sort: histogram -> 2-level exclusive scan -> placement --------------
__global__ void k_hist(const int* __restrict__ ei, int* __restrict__ deg){
  int e = blockIdx.x * 256 + threadIdx.x;
  if (e < EE) atomicAdd(&deg[ei[EE + e]], 1);
}

__global__ __launch_bounds__(256) void k_scan1(const int* __restrict__ deg,
                                               int* __restrict__ start,
                                               int* __restrict__ partial){
  __shared__ int sums[256];
  int b = blockIdx.x, tid = threadIdx.x;
  int base = b * 1024 + tid * 4;
  int d0 = (base + 0 < NN) ? deg[base + 0] : 0;
  int d1 = (base + 1 < NN) ? deg[base + 1] : 0;
  int d2 = (base + 2 < NN) ? deg[base + 2] : 0;
  int d3 = (base + 3 < NN) ? deg[base + 3] : 0;
  int s = d0 + d1 + d2 + d3;
  sums[tid] = s;
  __syncthreads();
  for (int off = 1; off < 256; off <<= 1){
    int v = (tid >= off) ? sums[tid - off] : 0;
    __syncthreads();
    sums[tid] += v;
    __syncthreads();
  }
  int excl = sums[tid] - s;
  if (base + 0 < NN) start[base + 0] = excl;
  if (base + 1 < NN) start[base + 1] = excl + d0;
  if (base + 2 < NN) start[base + 2] = excl + d0 + d1;
  if (base + 3 < NN) start[base + 3] = excl + d0 + d1 + d2;
  if (tid == 255) partial[b] = sums[255];
}

__global__ void k_scan2(int* __restrict__ partial){
  if (threadIdx.x == 0){
    int run = 0;
    for (int b = 0; b < NB_SCAN; b++){ int t = partial[b]; partial[b] = run; run += t; }
  }
}

__global__ void k_scan3(int* __restrict__ start, const int* __restrict__ partial,
                        int* __restrict__ cursor){
  int i = blockIdx.x * 256 + threadIdx.x;
  if (i < NN){
    int v = start[i] + partial[i >> 10];
    start[i] = v;
    cursor[i] = v;
  }
  if (i == 0) start[NN] = EE;
}

__global__ void k_place(const int* __restrict__ ei, int* __restrict__ cursor,
                        uint2* __restrict__ sorted2){
  int e = blockIdx.x * 256 + threadIdx.x;
  if (e < EE){
    int dst = ei[EE + e];
    int src = ei[e];
    int pos = atomicAdd(&cursor[dst], 1);
    sorted2[pos] = make_uint2((uint)e, (uint)src);  // pre-gathered src kills a dep load
  }
}

// ---------------- K3: per-node gather, unroll x4 for MLP ------------------------------
__global__ __launch_bounds__(256) void k_gather(
    const ushort* __restrict__ q_n, const ushort* __restrict__ kv,
    const ushort* __restrict__ ep, const int* __restrict__ start,
    const uint2* __restrict__ sorted2, float* __restrict__ out){
  int wave = (blockIdx.x * 256 + threadIdx.x) >> 6;
  if (wave >= NN) return;
  int n = wave;
  int l = threadIdx.x & 63;
  int c = l * 2;
  int s0 = start[n], s1 = start[n + 1];
  uint qq = *(const uint*)(q_n + (size_t)n * 128 + c);
  float q0 = bf2f(qq & 0xffff), q1 = bf2f(qq >> 16);
  float acc0 = 0.f, acc1 = 0.f, denom = 0.f;
  int i = s0;
  for (; i + 4 <= s1; i += 4){
    uint2 p0 = sorted2[i], p1 = sorted2[i+1], p2 = sorted2[i+2], p3 = sorted2[i+3];
    uint2 kv0 = *(const uint2*)(kv + (size_t)p0.y * 256 + c * 2);
    uint2 kv1 = *(const uint2*)(kv + (size_t)p1.y * 256 + c * 2);
    uint2 kv2 = *(const uint2*)(kv + (size_t)p2.y * 256 + c * 2);
    uint2 kv3 = *(const uint2*)(kv + (size_t)p3.y * 256 + c * 2);
    uint e0 = *(const uint*)(ep + (size_t)p0.x * 128 + c);
    uint e1 = *(const uint*)(ep + (size_t)p1.x * 128 + c);
    uint e2 = *(const uint*)(ep + (size_t)p2.x * 128 + c);
    uint e3 = *(const uint*)(ep + (size_t)p3.x * 128 + c);
    float pa0 = bf2f(e0 & 0xffff), pa1 = bf2f(e0 >> 16);
    float pb0 = bf2f(e1 & 0xffff), pb1 = bf2f(e1 >> 16);
    float pc0 = bf2f(e2 & 0xffff), pc1 = bf2f(e2 >> 16);
    float pd0 = bf2f(e3 & 0xffff), pd1 = bf2f(e3 >> 16);
    float ka = q0 * (bf2f(kv0.x & 0xffff) + pa0) + q1 * (bf2f(kv0.x >> 16) + pa1);
    float kb = q0 * (bf2f(kv1.x & 0xffff) + pb0) + q1 * (bf2f(kv1.x >> 16) + pb1);
    float kc = q0 * (bf2f(kv2.x & 0xffff) + pc0) + q1 * (bf2f(kv2.x >> 16) + pc1);
    float kd = q0 * (bf2f(kv3.x & 0xffff) + pd0) + q1 * (bf2f(kv3.x >> 16) + pd1);
    #pragma unroll
    for (int off = 16; off > 0; off >>= 1){
      ka += __shfl_xor(ka, off);
      kb += __shfl_xor(kb, off);
      kc += __shfl_xor(kc, off);
      kd += __shfl_xor(kd, off);
    }
    float ea = __expf(ka * 0.125f), eb = __expf(kb * 0.125f);
    float ec = __expf(kc * 0.125f), ed = __expf(kd * 0.125f);
    denom += (ea + eb) + (ec + ed);
    acc0 += ea * (bf2f(kv0.y & 0xffff) + pa0) + eb * (bf2f(kv1.y & 0xffff) + pb0)
          + ec * (bf2f(kv2.y & 0xffff) + pc0) + ed * (bf2f(kv3.y & 0xffff) + pd0);
    acc1 += ea * (bf2f(kv0.y >> 16) + pa1) + eb * (bf2f(kv1.y >> 16) + pb1)
          + ec * (bf2f(kv2.y >> 16) + pc1) + ed * (bf2f(kv3.y >> 16) + pd1);
  }
  for (; i + 2 <= s1; i += 2){
    uint2 p0 = sorted2[i], p1 = sorted2[i + 1];
    uint2 kv0 = *(const uint2*)(kv + (size_t)p0.y * 256 + c * 2);
    uint2 kv1 = *(const uint2*)(kv + (size_t)p1.y * 256 + c * 2);
    uint e0 = *(const uint*)(ep + (size_t)p0.x * 128 + c);
    uint e1 = *(const uint*)(ep + (size_t)p1.x * 128 + c);
    float pa0 = bf2f(e0 & 0xffff), pa1 = bf2f(e0 >> 16);
    float pb0 = bf2f(e1 & 0xffff), pb1 = bf2f(e1 >> 16);
    float ka = q0 * (bf2f(kv0.x & 0xffff) + pa0) + q1 * (bf2f(kv0.x >> 16) + pa1);
    float kb = q0 * (bf2f(kv1.x & 0xffff) + pb0) + q1 * (bf2f(kv1.x >> 16) + pb1);
    #pragma unroll
    for (int off = 16; off > 0; off >>= 1){
      ka += __shfl_xor(ka, off);
      kb += __shfl_xor(kb, off);
    }
    float ea = __expf(ka * 0.125f), eb = __expf(kb * 0.125f);
    denom += ea + eb;
    acc0 += ea * (bf2f(kv0.y & 0xffff) + pa0) + eb * (bf2f(kv1.y & 0xffff) + pb0);
    acc1 += ea * (bf2f(kv0.y >> 16) + pa1) + eb * (bf2f(kv1.y >> 16) + pb1);
  }
  if (i < s1){
    uint2 p0 = sorted2[i];
    uint2 kv0 = *(const uint2*)(kv + (size_t)p0.y * 256 + c * 2);
    uint e0 = *(const uint*)(ep + (size_t)p0.x * 128 + c);
    float pa0 = bf2f(e0 & 0xffff), pa1 = bf2f(e0 >> 16);
    float ka = q0 * (bf2f(kv0.x & 0xffff) + pa0) + q1 * (bf2f(kv0.x >> 16) + pa1);
    #pragma unroll
    for (int off = 16; off > 0; off >>= 1) ka += __shfl_xor(ka, off);
    float ea = __expf(ka * 0.125f);
    denom += ea;
    acc0 += ea * (bf2f(kv0.y & 0xffff) + pa0);
    acc1 += ea * (bf2f(kv0.y >> 16) + pa1);
  }
  float inv = 1.0f / (denom + 1e-16f);
  size_t o = (size_t)n * 128 + c;
  out[o]     += acc0 * inv;
  out[o + 1] += acc1 * inv;
}

extern "C" void kernel_launch(void* const* d_in, const int* in_sizes, int n_in,
                              void* d_out, int out_size, void* d_ws, size_t ws_size,
                              hipStream_t stream) {
  const float* x   = (const float*)d_in[0];
  const float* lu  = (const float*)d_in[1];
  const float* t   = (const float*)d_in[2];
  const float* msg = (const float*)d_in[3];
  const float* tw  = (const float*)d_in[4];
  const float* tb  = (const float*)d_in[5];
  const float* Wq  = (const float*)d_in[6];
  const float* bq  = (const float*)d_in[7];
  const float* Wk  = (const float*)d_in[8];
  const float* bk  = (const float*)d_in[9];
  const float* Wv  = (const float*)d_in[10];
  const float* bv  = (const float*)d_in[11];
  const float* We  = (const float*)d_in[12];
  const float* Wsk = (const float*)d_in[13];
  const float* bsk = (const float*)d_in[14];
  const int*   ei  = (const int*)d_in[15];
  float* out = (float*)d_out;

  char* w = (char*)d_ws;
  size_t off = 0;
  auto nxt = [&](size_t b){ size_t r = off; off += (b + 255) & ~(size_t)255; return r; };
  ushort* q_n   = (ushort*)(w + nxt((size_t)NN * 128 * 2));
  ushort* kv    = (ushort*)(w + nxt((size_t)NN * 256 * 2));
  ushort* epj   = (ushort*)(w + nxt((size_t)EE * 128 * 2));
  ushort* W4t   = (ushort*)(w + nxt((size_t)512 * 128 * 2));
  ushort* Wet   = (ushort*)(w + nxt((size_t)128 * 256 * 2));
  int* deg      = (int*)(w + nxt((size_t)NN * 4));
  int* start    = (int*)(w + nxt((size_t)(NN + 1) * 4));
  int* cursor   = (int*)(w + nxt((size_t)NN * 4));
  int* partial  = (int*)(w + nxt((size_t)(NB_SCAN + 1) * 4));
  uint2* sorted2 = (uint2*)(w + nxt((size_t)EE * 8));
  float* rel    = (float*)(w + nxt((size_t)EE * 4));

  k_prep<<<(NN + 255) / 256, 256, 0, stream>>>(Wq, Wk, Wv, Wsk, We, W4t, Wet, deg);
  k_node<<<(NN + 63) / 64, 256, 0, stream>>>(x, W4t, bq, bk, bv, bsk, q_n, kv, out);
  k_rel<<<(EE + 255) / 256, 256, 0, stream>>>(t, lu, ei, rel);
  k_edge7<<<G_E7, 512, 0, stream>>>(rel, msg, tw, tb, Wet, epj);
  k_hist<<<(EE + 255) / 256, 256, 0, stream>>>(ei, deg);
  k_scan1<<<NB_SCAN, 256, 0, stream>>>(deg, start, partial);
  k_scan2<<<1, 64, 0, stream>>>(partial);
  k_scan3<<<(NN + 255) / 256, 256, 0, stream>>>(start, partial, cursor);
  k_place<<<(EE + 255) / 256, 256, 0, stream>>>(ei, cursor, sorted2);
  k_gather<<<(NN * 64 + 255) / 256, 256, 0, stream>>>(q_n, kv, epj, start, sorted2, out);
}

// Round 9
// 464.043 us; speedup vs baseline: 2.4768x; 2.4768x over previous
//
#include <hip/hip_runtime.h>
#include <hip/hip_bf16.h>

#define NN 100000
#define EE 640000
#define NB_SCAN 98   // ceil(NN/1024)
#define G_E3 2048    // k_edge3 blocks (8192 waves; 40000 tile-pairs)

typedef short bf16x8 __attribute__((ext_vector_type(8)));
typedef float f32x4 __attribute__((ext_vector_type(4)));

__device__ __forceinline__ ushort f2bf(float f){
  uint u = __float_as_uint(f);
  u += 0x7fffu + ((u >> 16) & 1u);   // round-to-nearest-even
  return (ushort)(u >> 16);
}
__device__ __forceinline__ float bf2f(ushort s){ return __uint_as_float(((uint)s) << 16); }
__device__ __forceinline__ uint pack2(float a, float b){ return ((uint)f2bf(b) << 16) | (uint)f2bf(a); }
__device__ __forceinline__ uint swz(uint row, uint colB, uint strideB){
  return row * strideB + (colB ^ ((row & 7u) << 4));
}

// ---------------- K0: weight prep (fp32 -> bf16, transposed [col][k]) + zero deg -----
__global__ void k_prep(const float* __restrict__ Wq, const float* __restrict__ Wk,
                       const float* __restrict__ Wv, const float* __restrict__ Wsk,
                       const float* __restrict__ We,
                       ushort* __restrict__ W4t, ushort* __restrict__ Wet,
                       int* __restrict__ deg){
  int tid = blockIdx.x * 256 + threadIdx.x;
  if (tid < 512 * 128){              // W4t[col 0..511][k 0..127], cols: q|k|v|skip
    int col = tid >> 7, k = tid & 127;
    const float* W = (col < 128) ? Wq : ((col < 256) ? Wk : ((col < 384) ? Wv : Wsk));
    W4t[tid] = f2bf(W[k * 128 + (col & 127)]);
  }
  if (tid < 128 * 256){              // Wet[col 0..127][k 0..255]
    int col = tid >> 8, k = tid & 255;
    Wet[tid] = f2bf(We[k * 128 + col]);
  }
  if (tid < NN) deg[tid] = 0;
}

// ---------------- K1: node GEMM x@[Wq|Wk|Wv|Wskip], 64-row tiles, bf16 MFMA ----------
__global__ __launch_bounds__(256) void k_node(
    const float* __restrict__ x, const ushort* __restrict__ W4t,
    const float* __restrict__ bq, const float* __restrict__ bk,
    const float* __restrict__ bv, const float* __restrict__ bsk,
    ushort* __restrict__ q_n, ushort* __restrict__ kv,
    float* __restrict__ out){
  __shared__ ushort As[64 * 128];
  __shared__ ushort Bs[128 * 128];
  char* Ab = (char*)As; char* Bb = (char*)Bs;
  int tid = threadIdx.x;
  int n0 = blockIdx.x * 64;
  {
    int row = tid >> 2, part = tid & 3;
    int gr = n0 + row;
    for (int j = 0; j < 4; j++){
      float4 a = make_float4(0.f,0.f,0.f,0.f), b = a;
      if (gr < NN){
        const float4* p = (const float4*)(x + (size_t)gr * 128 + part * 32 + j * 8);
        a = p[0]; b = p[1];
      }
      uint4 w; w.x = pack2(a.x,a.y); w.y = pack2(a.z,a.w); w.z = pack2(b.x,b.y); w.w = pack2(b.z,b.w);
      *(uint4*)(Ab + swz(row, (uint)(part * 64 + j * 16), 256)) = w;
    }
  }
  int wid = tid >> 6, l = tid & 63, lr = l & 15, lg = l >> 4;
  for (int chunk = 0; chunk < 4; ++chunk){
    if (chunk) __syncthreads();
    {
      int row = tid >> 1, half = tid & 1;
      const ushort* src = W4t + (size_t)(chunk * 128 + row) * 128 + half * 64;
      for (int j = 0; j < 8; j++){
        uint4 w = *(const uint4*)(src + j * 8);
        *(uint4*)(Bb + swz(row, (uint)(half * 128 + j * 16), 256)) = w;
      }
    }
    __syncthreads();
    f32x4 acc[8];
    for (int i = 0; i < 8; i++) acc[i] = (f32x4){0.f,0.f,0.f,0.f};
    for (int ks = 0; ks < 4; ++ks){
      bf16x8 a = *(bf16x8*)(Ab + swz(wid * 16 + lr, (uint)(ks * 64 + lg * 16), 256));
      for (int cf = 0; cf < 8; ++cf){
        bf16x8 b = *(bf16x8*)(Bb + swz(cf * 16 + lr, (uint)(ks * 64 + lg * 16), 256));
        acc[cf] = __builtin_amdgcn_mfma_f32_16x16x32_bf16(a, b, acc[cf], 0, 0, 0);
      }
    }
    for (int cf = 0; cf < 8; ++cf){
      for (int i = 0; i < 4; i++){
        int row = wid * 16 + lg * 4 + i;
        int gr = n0 + row;
        if (gr >= NN) continue;
        int col = cf * 16 + lr;
        float v = acc[cf][i];
        if (chunk == 0)      q_n[(size_t)gr * 128 + col] = f2bf(v + bq[col]);
        else if (chunk == 1) kv[(size_t)gr * 256 + ((col >> 1) << 2) + (col & 1)]     = f2bf(v + bk[col]);
        else if (chunk == 2) kv[(size_t)gr * 256 + ((col >> 1) << 2) + 2 + (col & 1)] = f2bf(v + bv[col]);
        else                 out[(size_t)gr * 128 + col] = v + bsk[col];
      }
    }
  }
}

// ---------------- k_rel: rel[e] = t[e] - lu[src[e]] ----------------------------------
__global__ void k_rel(const float* __restrict__ tt, const float* __restrict__ lu,
                      const int* __restrict__ ei, float* __restrict__ rel){
  int e = blockIdx.x * 256 + threadIdx.x;
  if (e < EE) rel[e] = tt[e] - lu[ei[e]];
}

// ---------------- K2 v3 (proven best): streaming edge GEMM, no LDS, no barriers ------
// A = We^T half (64 ch x K=256) in 128 VGPRs; B = edge features in registers
// (lane lr = edge, lg = k-octet): k<128 cos, k>=128 msg direct row slice.
// Wave pairs share an edge group (second msg read mostly L1/L2).
__global__ __launch_bounds__(256, 2) void k_edge3(
    const float* __restrict__ rel, const float* __restrict__ msg,
    const float* __restrict__ tw, const float* __restrict__ tb,
    const ushort* __restrict__ Wet, ushort* __restrict__ ep){
  int tid = threadIdx.x;
  int wid = tid >> 6, l = tid & 63, lr = l & 15, lg = l >> 4;
  int gw = (int)blockIdx.x * 4 + wid;   // global wave id (8192 total)
  int half = gw & 1;                    // channel half: 0 -> ch 0..63, 1 -> ch 64..127
  bf16x8 Af[4][8];
  const char* WB = (const char*)Wet;
  #pragma unroll
  for (int rt = 0; rt < 4; ++rt)
    #pragma unroll
    for (int ks = 0; ks < 8; ++ks)
      Af[rt][ks] = *(const bf16x8*)(WB + (size_t)(half*64 + rt*16 + lr)*512 + ks*64 + lg*16);

  for (int g = gw >> 1; g < EE/16; g += G_E3 * 2){
    int e0 = g * 16;
    float4 m[8];
    const float* MB = msg + (size_t)(e0 + lr) * 128 + lg * 8;
    #pragma unroll
    for (int ks = 0; ks < 4; ++ks){
      m[2*ks]   = *(const float4*)(MB + ks * 32);
      m[2*ks+1] = *(const float4*)(MB + ks * 32 + 4);
    }
    float relv = rel[e0 + lr];
    bf16x8 B[8];
    #pragma unroll
    for (int ks = 0; ks < 4; ++ks){     // k = ks*32 + lg*8 : cos features
      int k0 = ks * 32 + lg * 8;
      float4 wa = *(const float4*)(tw + k0), wb = *(const float4*)(tw + k0 + 4);
      float4 ba = *(const float4*)(tb + k0), bb = *(const float4*)(tb + k0 + 4);
      float c0 = __cosf(fmaf(relv, wa.x, ba.x));
      float c1 = __cosf(fmaf(relv, wa.y, ba.y));
      float c2 = __cosf(fmaf(relv, wa.z, ba.z));
      float c3 = __cosf(fmaf(relv, wa.w, ba.w));
      float c4 = __cosf(fmaf(relv, wb.x, bb.x));
      float c5 = __cosf(fmaf(relv, wb.y, bb.y));
      float c6 = __cosf(fmaf(relv, wb.z, bb.z));
      float c7 = __cosf(fmaf(relv, wb.w, bb.w));
      uint4 w; w.x = pack2(c0,c1); w.y = pack2(c2,c3); w.z = pack2(c4,c5); w.w = pack2(c6,c7);
      B[ks] = *(bf16x8*)&w;
    }
    #pragma unroll
    for (int ks = 0; ks < 4; ++ks){     // k = 128 + ks*32 + lg*8 : msg features
      float4 a = m[2*ks], b = m[2*ks+1];
      uint4 w; w.x = pack2(a.x,a.y); w.y = pack2(a.z,a.w); w.z = pack2(b.x,b.y); w.w = pack2(b.z,b.w);
      B[4+ks] = *(bf16x8*)&w;
    }
    f32x4 acc[4];
    #pragma unroll
    for (int rt = 0; rt < 4; ++rt) acc[rt] = (f32x4){0.f,0.f,0.f,0.f};
    #pragma unroll
    for (int ks = 0; ks < 8; ++ks)
      #pragma unroll
      for (int rt = 0; rt < 4; ++rt)
        acc[rt] = __builtin_amdgcn_mfma_f32_16x16x32_bf16(Af[rt][ks], B[ks], acc[rt], 0, 0, 0);
    // D: col = lane&15 = edge, row = (lane>>4)*4+i = channel -> 4 contiguous ushorts
    #pragma unroll
    for (int rt = 0; rt < 4; ++rt){
      uint2 w = make_uint2(pack2(acc[rt][0], acc[rt][1]), pack2(acc[rt][2], acc[rt][3]));
      *(uint2*)(ep + (size_t)(e0 + lr) * 128 + half * 64 + rt * 16 + lg * 4) = w;
    }
  }
}

// ---------------- Sort: histogram -> 2-level exclusive scan -> placement --------------
__global__ void k_hist(const int* __restrict__ ei, int* __restrict__ deg){
  int e = blockIdx.x * 256 + threadIdx.x;
  if (e < EE) atomicAdd(&deg[ei[EE + e]], 1);
}

__global__ __launch_bounds__(256) void k_scan1(const int* __restrict__ deg,
                                               int* __restrict__ start,
                                               int* __restrict__ partial){
  __shared__ int sums[256];
  int b = blockIdx.x, tid = threadIdx.x;
  int base = b * 1024 + tid * 4;
  int d0 = (base + 0 < NN) ? deg[base + 0] : 0;
  int d1 = (base + 1 < NN) ? deg[base + 1] : 0;
  int d2 = (base + 2 < NN) ? deg[base + 2] : 0;
  int d3 = (base + 3 < NN) ? deg[base + 3] : 0;
  int s = d0 + d1 + d2 + d3;
  sums[tid] = s;
  __syncthreads();
  for (int off = 1; off < 256; off <<= 1){
    int v = (tid >= off) ? sums[tid - off] : 0;
    __syncthreads();
    sums[tid] += v;
    __syncthreads();
  }
  int excl = sums[tid] - s;
  if (base + 0 < NN) start[base + 0] = excl;
  if (base + 1 < NN) start[base + 1] = excl + d0;
  if (base + 2 < NN) start[base + 2] = excl + d0 + d1;
  if (base + 3 < NN) start[base + 3] = excl + d0 + d1 + d2;
  if (tid == 255) partial[b] = sums[255];
}

__global__ void k_scan2(int* __restrict__ partial){
  if (threadIdx.x == 0){
    int run = 0;
    for (int b = 0; b < NB_SCAN; b++){ int t = partial[b]; partial[b] = run; run += t; }
  }
}

__global__ void k_scan3(int* __restrict__ start, const int* __restrict__ partial,
                        int* __restrict__ cursor){
  int i = blockIdx.x * 256 + threadIdx.x;
  if (i < NN){
    int v = start[i] + partial[i >> 10];
    start[i] = v;
    cursor[i] = v;
  }
  if (i == 0) start[NN] = EE;
}

__global__ void k_place(const int* __restrict__ ei, int* __restrict__ cursor,
                        uint2* __restrict__ sorted2){
  int e = blockIdx.x * 256 + threadIdx.x;
  if (e < EE){
    int dst = ei[EE + e];
    int src = ei[e];
    int pos = atomicAdd(&cursor[dst], 1);
    sorted2[pos] = make_uint2((uint)e, (uint)src);  // pre-gathered src kills a dep load
  }
}

// ---------------- K3: per-node gather, unroll x4 for MLP ------------------------------
__global__ __launch_bounds__(256) void k_gather(
    const ushort* __restrict__ q_n, const ushort* __restrict__ kv,
    const ushort* __restrict__ ep, const int* __restrict__ start,
    const uint2* __restrict__ sorted2, float* __restrict__ out){
  int wave = (blockIdx.x * 256 + threadIdx.x) >> 6;
  if (wave >= NN) return;
  int n = wave;
  int l = threadIdx.x & 63;
  int c = l * 2;
  int s0 = start[n], s1 = start[n + 1];
  uint qq = *(const uint*)(q_n + (size_t)n * 128 + c);
  float q0 = bf2f(qq & 0xffff), q1 = bf2f(qq >> 16);
  float acc0 = 0.f, acc1 = 0.f, denom = 0.f;
  int i = s0;
  for (; i + 4 <= s1; i += 4){
    uint2 p0 = sorted2[i], p1 = sorted2[i+1], p2 = sorted2[i+2], p3 = sorted2[i+3];
    uint2 kv0 = *(const uint2*)(kv + (size_t)p0.y * 256 + c * 2);
    uint2 kv1 = *(const uint2*)(kv + (size_t)p1.y * 256 + c * 2);
    uint2 kv2 = *(const uint2*)(kv + (size_t)p2.y * 256 + c * 2);
    uint2 kv3 = *(const uint2*)(kv + (size_t)p3.y * 256 + c * 2);
    uint e0 = *(const uint*)(ep + (size_t)p0.x * 128 + c);
    uint e1 = *(const uint*)(ep + (size_t)p1.x * 128 + c);
    uint e2 = *(const uint*)(ep + (size_t)p2.x * 128 + c);
    uint e3 = *(const uint*)(ep + (size_t)p3.x * 128 + c);
    float pa0 = bf2f(e0 & 0xffff), pa1 = bf2f(e0 >> 16);
    float pb0 = bf2f(e1 & 0xffff), pb1 = bf2f(e1 >> 16);
    float pc0 = bf2f(e2 & 0xffff), pc1 = bf2f(e2 >> 16);
    float pd0 = bf2f(e3 & 0xffff), pd1 = bf2f(e3 >> 16);
    float ka = q0 * (bf2f(kv0.x & 0xffff) + pa0) + q1 * (bf2f(kv0.x >> 16) + pa1);
    float kb = q0 * (bf2f(kv1.x & 0xffff) + pb0) + q1 * (bf2f(kv1.x >> 16) + pb1);
    float kc = q0 * (bf2f(kv2.x & 0xffff) + pc0) + q1 * (bf2f(kv2.x >> 16) + pc1);
    float kd = q0 * (bf2f(kv3.x & 0xffff) + pd0) + q1 * (bf2f(kv3.x >> 16) + pd1);
    #pragma unroll
    for (int off = 16; off > 0; off >>= 1){
      ka += __shfl_xor(ka, off);
      kb += __shfl_xor(kb, off);
      kc += __shfl_xor(kc, off);
      kd += __shfl_xor(kd, off);
    }
    float ea = __expf(ka * 0.125f), eb = __expf(kb * 0.125f);
    float ec = __expf(kc * 0.125f), ed = __expf(kd * 0.125f);
    denom += (ea + eb) + (ec + ed);
    acc0 += ea * (bf2f(kv0.y & 0xffff) + pa0) + eb * (bf2f(kv1.y & 0xffff) + pb0)
          + ec * (bf2f(kv2.y & 0xffff) + pc0) + ed * (bf2f(kv3.y & 0xffff) + pd0);
    acc1 += ea * (bf2f(kv0.y >> 16) + pa1) + eb * (bf2f(kv1.y >> 16) + pb1)
          + ec * (bf2f(kv2.y >> 16) + pc1) + ed * (bf2f(kv3.y >> 16) + pd1);
  }
  for (; i + 2 <= s1; i += 2){
    uint2 p0 = sorted2[i], p1 = sorted2[i + 1];
    uint2 kv0 = *(const uint2*)(kv + (size_t)p0.y * 256 + c * 2);
    uint2 kv1 = *(const uint2*)(kv + (size_t)p1.y * 256 + c * 2);
    uint e0 = *(const uint*)(ep + (size_t)p0.x * 128 + c);
    uint e1 = *(const uint*)(ep + (size_t)p1.x * 128 + c);
    float pa0 = bf2f(e0 & 0xffff), pa1 = bf2f(e0 >> 16);
    float pb0 = bf2f(e1 & 0xffff), pb1 = bf2f(e1 >> 16);
    float ka = q0 * (bf2f(kv0.x & 0xffff) + pa0) + q1 * (bf2f(kv0.x >> 16) + pa1);
    float kb = q0 * (bf2f(kv1.x & 0xffff) + pb0) + q1 * (bf2f(kv1.x >> 16) + pb1);
    #pragma unroll
    for (int off = 16; off > 0; off >>= 1){
      ka += __shfl_xor(ka, off);
      kb += __shfl_xor(kb, off);
    }
    float ea = __expf(ka * 0.125f), eb = __expf(kb * 0.125f);
    denom += ea + eb;
    acc0 += ea * (bf2f(kv0.y & 0xffff) + pa0) + eb * (bf2f(kv1.y & 0xffff) + pb0);
    acc1 += ea * (bf2f(kv0.y >> 16) + pa1) + eb * (bf2f(kv1.y >> 16) + pb1);
  }
  if (i < s1){
    uint2 p0 = sorted2[i];
    uint2 kv0 = *(const uint2*)(kv + (size_t)p0.y * 256 + c * 2);
    uint e0 = *(const uint*)(ep + (size_t)p0.x * 128 + c);
    float pa0 = bf2f(e0 & 0xffff), pa1 = bf2f(e0 >> 16);
    float ka = q0 * (bf2f(kv0.x & 0xffff) + pa0) + q1 * (bf2f(kv0.x >> 16) + pa1);
    #pragma unroll
    for (int off = 16; off > 0; off >>= 1) ka += __shfl_xor(ka, off);
    float ea = __expf(ka * 0.125f);
    denom += ea;
    acc0 += ea * (bf2f(kv0.y & 0xffff) + pa0);
    acc1 += ea * (bf2f(kv0.y >> 16) + pa1);
  }
  float inv = 1.0f / (denom + 1e-16f);
  size_t o = (size_t)n * 128 + c;
  out[o]     += acc0 * inv;
  out[o + 1] += acc1 * inv;
}

extern "C" void kernel_launch(void* const* d_in, const int* in_sizes, int n_in,
                              void* d_out, int out_size, void* d_ws, size_t ws_size,
                              hipStream_t stream) {
  const float* x   = (const float*)d_in[0];
  const float* lu  = (const float*)d_in[1];
  const float* t   = (const float*)d_in[2];
  const float* msg = (const float*)d_in[3];
  const float* tw  = (const float*)d_in[4];
  const float* tb  = (const float*)d_in[5];
  const float* Wq  = (const float*)d_in[6];
  const float* bq  = (const float*)d_in[7];
  const float* Wk  = (const float*)d_in[8];
  const float* bk  = (const float*)d_in[9];
  const float* Wv  = (const float*)d_in[10];
  const float* bv  = (const float*)d_in[11];
  const float* We  = (const float*)d_in[12];
  const float* Wsk = (const float*)d_in[13];
  const float* bsk = (const float*)d_in[14];
  const int*   ei  = (const int*)d_in[15];
  float* out = (float*)d_out;

  char* w = (char*)d_ws;
  size_t off = 0;
  auto nxt = [&](size_t b){ size_t r = off; off += (b + 255) & ~(size_t)255; return r; };
  ushort* q_n   = (ushort*)(w + nxt((size_t)NN * 128 * 2));
  ushort* kv    = (ushort*)(w + nxt((size_t)NN * 256 * 2));
  ushort* epj   = (ushort*)(w + nxt((size_t)EE * 128 * 2));
  ushort* W4t   = (ushort*)(w + nxt((size_t)512 * 128 * 2));
  ushort* Wet   = (ushort*)(w + nxt((size_t)128 * 256 * 2));
  int* deg      = (int*)(w + nxt((size_t)NN * 4));
  int* start    = (int*)(w + nxt((size_t)(NN + 1) * 4));
  int* cursor   = (int*)(w + nxt((size_t)NN * 4));
  int* partial  = (int*)(w + nxt((size_t)(NB_SCAN + 1) * 4));
  uint2* sorted2 = (uint2*)(w + nxt((size_t)EE * 8));
  float* rel    = (float*)(w + nxt((size_t)EE * 4));

  k_prep<<<(NN + 255) / 256, 256, 0, stream>>>(Wq, Wk, Wv, Wsk, We, W4t, Wet, deg);
  k_node<<<(NN + 63) / 64, 256, 0, stream>>>(x, W4t, bq, bk, bv, bsk, q_n, kv, out);
  k_rel<<<(EE + 255) / 256, 256, 0, stream>>>(t, lu, ei, rel);
  k_edge3<<<G_E3, 256, 0, stream>>>(rel, msg, tw, tb, Wet, epj);
  k_hist<<<(EE + 255) / 256, 256, 0, stream>>>(ei, deg);
  k_scan1<<<NB_SCAN, 256, 0, stream>>>(deg, start, partial);
  k_scan2<<<1, 64, 0, stream>>>(partial);
  k_scan3<<<(NN + 255) / 256, 256, 0, stream>>>(start, partial, cursor);
  k_place<<<(EE + 255) / 256, 256, 0, stream>>>(ei, cursor, sorted2);
  k_gather<<<(NN * 64 + 255) / 256, 256, 0, stream>>>(q_n, kv, epj, start, sorted2, out);
}